// Round 1
// baseline (89.969 us; speedup 1.0000x reference)
//
#include <hip/hip_runtime.h>
#include <hip/hip_bf16.h>

typedef short s4 __attribute__((ext_vector_type(4)));
typedef short s8 __attribute__((ext_vector_type(8)));
typedef float f4 __attribute__((ext_vector_type(4)));

#define MFMA16(a, b, c) __builtin_amdgcn_mfma_f32_16x16x16bf16_1k(a, b, c, 0, 0, 0)

__device__ __forceinline__ short f2bf(float f) {
    union { float f; unsigned u; } v; v.f = f;
    unsigned r = v.u + 0x7fffu + ((v.u >> 16) & 1u);   // RNE
    return (short)(r >> 16);
}

// ---------------------------------------------------------------------------
// Kernel 1: projections  out[16384,64](bf16) = X[16384,1024] @ W[1024,64] + b
// grid (256, 3), block 256 (4 waves). BM=64, BK=64, bf16 MFMA 16x16x16.
// ---------------------------------------------------------------------------
struct ProjArgs {
    const float* X[3];
    const float* W[3];
    const float* b[3];
    unsigned short* O[3];
};

__global__ __launch_bounds__(256) void proj_kernel(ProjArgs args) {
    __shared__ short lA[64][68];   // [row][k]  stride 136B (34 dw -> conflict-free b64 reads)
    __shared__ short lW[64][68];   // [k][n]    scalar reads, conflict-free (lanes span 32B rows)

    const int t  = threadIdx.x;
    const int wv = t >> 6, ln = t & 63, lg = ln >> 4, lr = ln & 15;
    const int which = blockIdx.y;

    const float* X = args.X[which] + (size_t)blockIdx.x * 64 * 1024;
    const float* W = args.W[which];

    f4 acc[4] = {f4{0,0,0,0}, f4{0,0,0,0}, f4{0,0,0,0}, f4{0,0,0,0}};

    for (int kk = 0; kk < 1024; kk += 64) {
        // stage A (64x64 f32 -> bf16) and W (64x64 f32 -> bf16), both row-major
        #pragma unroll
        for (int i = 0; i < 4; ++i) {
            int f  = t + i * 256;       // float4 index, 0..1023
            int r  = f >> 4;            // 16 float4 per row
            int c4 = f & 15;
            f4 a = *(const f4*)(X + (size_t)r * 1024 + kk + c4 * 4);
            f4 w = *(const f4*)(W + (size_t)(kk + r) * 64 + c4 * 4);
            s4 ab; ab[0]=f2bf(a[0]); ab[1]=f2bf(a[1]); ab[2]=f2bf(a[2]); ab[3]=f2bf(a[3]);
            s4 wb; wb[0]=f2bf(w[0]); wb[1]=f2bf(w[1]); wb[2]=f2bf(w[2]); wb[3]=f2bf(w[3]);
            *(s4*)&lA[r][c4 * 4] = ab;
            *(s4*)&lW[r][c4 * 4] = wb;
        }
        __syncthreads();

        #pragma unroll
        for (int ks = 0; ks < 4; ++ks) {
            s4 af = *(const s4*)&lA[wv * 16 + lr][ks * 16 + 4 * lg];
            #pragma unroll
            for (int nf = 0; nf < 4; ++nf) {
                s4 bf;
                #pragma unroll
                for (int e = 0; e < 4; ++e)
                    bf[e] = lW[ks * 16 + 4 * lg + e][nf * 16 + lr];
                acc[nf] = MFMA16(af, bf, acc[nf]);
            }
        }
        __syncthreads();
    }

    // epilogue: + bias, convert to bf16, store
    const float* bias = args.b[which];
    unsigned short* O = args.O[which] + (size_t)blockIdx.x * 64 * 64;
    #pragma unroll
    for (int nf = 0; nf < 4; ++nf) {
        float bs = bias[nf * 16 + lr];
        #pragma unroll
        for (int e = 0; e < 4; ++e) {
            int r = wv * 16 + 4 * lg + e;
            O[(size_t)r * 64 + nf * 16 + lr] = (unsigned short)f2bf(acc[nf][e] + bs);
        }
    }
}

// ---------------------------------------------------------------------------
// Kernel 2: causal flash attention.
// grid (32, 8): x = q-tile (64 rows), y = batch. block 256 (4 waves, 16 q-rows each).
// Swapped-operand trick: S^T = K·Q^T so softmax is lane-local (scalar m, l)
// and P^T goes straight into the PV MFMA as a B-fragment.
// ---------------------------------------------------------------------------
__global__ __launch_bounds__(256) void attn_kernel(const unsigned short* __restrict__ qp,
                                                   const unsigned short* __restrict__ kp,
                                                   const unsigned short* __restrict__ vp,
                                                   float* __restrict__ out) {
    __shared__ short lK[64][72];   // [key][d]          stride 144B
    __shared__ short lV[64][76];   // [d][key] (transposed)  stride 152B

    const int t  = threadIdx.x;
    const int wv = t >> 6, ln = t & 63, lg = ln >> 4, lr = ln & 15;
    const int b  = blockIdx.y, qt = blockIdx.x;
    const int q0 = qt * 64;
    const int qrow = q0 + wv * 16 + lr;           // this lane's q row

    const unsigned short* qpb = qp + (size_t)b * 2048 * 64;

    // Q fragments (B-operand of K·Q^T): lane holds qp[qrow][4*lg+e] per ks
    s4 qf[4];
    #pragma unroll
    for (int ks = 0; ks < 4; ++ks)
        qf[ks] = *(const s4*)(qpb + (size_t)qrow * 64 + ks * 16 + 4 * lg);

    f4 accO[4] = {f4{0,0,0,0}, f4{0,0,0,0}, f4{0,0,0,0}, f4{0,0,0,0}};
    float m = -3e38f, lsum = 0.f;

    for (int kt = 0; kt <= qt; ++kt) {
        const unsigned short* kpb = kp + ((size_t)b * 2048 + kt * 64) * 64;
        const unsigned short* vpb = vp + ((size_t)b * 2048 + kt * 64) * 64;

        // stage K row-major, V transposed
        #pragma unroll
        for (int i = 0; i < 2; ++i) {
            int f = t + i * 256;       // 8-elem chunk index, 0..511
            int r = f >> 3, c8 = f & 7;
            s8 k8 = *(const s8*)(kpb + (size_t)r * 64 + c8 * 8);
            *(s8*)&lK[r][c8 * 8] = k8;
            s8 v8 = *(const s8*)(vpb + (size_t)r * 64 + c8 * 8);
            #pragma unroll
            for (int j = 0; j < 8; ++j) lV[c8 * 8 + j][r] = v8[j];
        }
        __syncthreads();

        // S^T[key = kf*16 + 4*lg + e][q = lr]
        f4 st[4];
        #pragma unroll
        for (int kf = 0; kf < 4; ++kf) {
            f4 a = f4{0,0,0,0};
            #pragma unroll
            for (int ks = 0; ks < 4; ++ks) {
                s4 kfr = *(const s4*)&lK[kf * 16 + lr][ks * 16 + 4 * lg];
                a = MFMA16(kfr, qf[ks], a);
            }
            st[kf] = a;
        }

        // scale + causal mask + online softmax (lane-local row)
        const bool diag = (kt == qt);
        const int kbase = kt * 64;
        float smax = -3e38f;
        #pragma unroll
        for (int kf = 0; kf < 4; ++kf) {
            #pragma unroll
            for (int e = 0; e < 4; ++e) {
                float s = st[kf][e] * 0.125f;
                if (diag && (kbase + kf * 16 + 4 * lg + e > qrow)) s = -3e38f;
                st[kf][e] = s;
                smax = fmaxf(smax, s);
            }
        }
        smax = fmaxf(smax, __shfl_xor(smax, 16));
        smax = fmaxf(smax, __shfl_xor(smax, 32));

        float mnew  = fmaxf(m, smax);
        float scale = __expf(m - mnew);
        float psum  = 0.f;
        s4 pf[4];
        #pragma unroll
        for (int kf = 0; kf < 4; ++kf) {
            f4 p;
            #pragma unroll
            for (int e = 0; e < 4; ++e) { p[e] = __expf(st[kf][e] - mnew); psum += p[e]; }
            s4 pb; pb[0]=f2bf(p[0]); pb[1]=f2bf(p[1]); pb[2]=f2bf(p[2]); pb[3]=f2bf(p[3]);
            pf[kf] = pb;
        }
        psum += __shfl_xor(psum, 16);
        psum += __shfl_xor(psum, 32);
        lsum = lsum * scale + psum;
        m = mnew;
        #pragma unroll
        for (int df = 0; df < 4; ++df) accO[df] *= scale;

        // O^T += V^T · P^T : lane holds O^T[d = df*16+4*lg+e][q = lr]
        #pragma unroll
        for (int df = 0; df < 4; ++df) {
            #pragma unroll
            for (int kf = 0; kf < 4; ++kf) {
                s4 vf = *(const s4*)&lV[df * 16 + lr][kf * 16 + 4 * lg];
                accO[df] = MFMA16(vf, pf[kf], accO[df]);
            }
        }
        __syncthreads();
    }

    // write O[q][d] = accO / lsum   (float4 per df)
    float inv = 1.f / lsum;
    float* ob = out + ((size_t)b * 2048 + qrow) * 64;
    #pragma unroll
    for (int df = 0; df < 4; ++df) {
        f4 o;
        #pragma unroll
        for (int e = 0; e < 4; ++e) o[e] = accO[df][e] * inv;
        *(f4*)(ob + df * 16 + 4 * lg) = o;
    }
}

// ---------------------------------------------------------------------------
extern "C" void kernel_launch(void* const* d_in, const int* in_sizes, int n_in,
                              void* d_out, int out_size, void* d_ws, size_t ws_size,
                              hipStream_t stream) {
    const float* q  = (const float*)d_in[0];
    const float* k  = (const float*)d_in[1];
    const float* v  = (const float*)d_in[2];
    // d_in[3] = causal mask (deterministic tril) — computed analytically
    const float* Wq = (const float*)d_in[4];
    const float* bq = (const float*)d_in[5];
    const float* Wk = (const float*)d_in[6];
    const float* bk = (const float*)d_in[7];
    const float* Wv = (const float*)d_in[8];
    const float* bv = (const float*)d_in[9];

    unsigned short* qp = (unsigned short*)d_ws;            // [16384][64] bf16
    unsigned short* kp = qp + (size_t)16384 * 64;
    unsigned short* vp = kp + (size_t)16384 * 64;

    ProjArgs pa;
    pa.X[0] = q;  pa.X[1] = k;  pa.X[2] = v;
    pa.W[0] = Wq; pa.W[1] = Wk; pa.W[2] = Wv;
    pa.b[0] = bq; pa.b[1] = bk; pa.b[2] = bv;
    pa.O[0] = qp; pa.O[1] = kp; pa.O[2] = vp;

    proj_kernel<<<dim3(256, 3), 256, 0, stream>>>(pa);
    attn_kernel<<<dim3(32, 8), 256, 0, stream>>>(qp, kp, vp, (float*)d_out);
}